// Round 6
// baseline (246.932 us; speedup 1.0000x reference)
//
#include <hip/hip_runtime.h>

typedef _Float16 half8_t __attribute__((ext_vector_type(8)));
typedef _Float16 half4_t __attribute__((ext_vector_type(4)));
typedef __fp16   fp16x2  __attribute__((ext_vector_type(2)));
typedef float    f32x4  __attribute__((ext_vector_type(4)));

#define MFMA32(a, b, c) __builtin_amdgcn_mfma_f32_16x16x32_f16((a), (b), (c), 0, 0, 0)
#define MFMA16(a, b, c) __builtin_amdgcn_mfma_f32_16x16x16f16((a), (b), (c), 0, 0, 0)

// 4x f32 -> half4 via 2x v_cvt_pkrtz_f16_f32
__device__ __forceinline__ half4_t pk4(f32x4 v) {
    fp16x2 lo = __builtin_amdgcn_cvt_pkrtz(v[0], v[1]);
    fp16x2 hi = __builtin_amdgcn_cvt_pkrtz(v[2], v[3]);
    half4_t r;
    r[0] = (_Float16)lo[0]; r[1] = (_Float16)lo[1];
    r[2] = (_Float16)hi[0]; r[3] = (_Float16)hi[1];
    return r;
}
__device__ __forceinline__ f32x4 exp2v(f32x4 v) {
    f32x4 r;
    r[0] = __builtin_amdgcn_exp2f(v[0]);
    r[1] = __builtin_amdgcn_exp2f(v[1]);
    r[2] = __builtin_amdgcn_exp2f(v[2]);
    r[3] = __builtin_amdgcn_exp2f(v[3]);
    return r;
}
__device__ __forceinline__ f32x4 rcpv(f32x4 v) {
    f32x4 r;
    r[0] = __builtin_amdgcn_rcpf(v[0]);
    r[1] = __builtin_amdgcn_rcpf(v[1]);
    r[2] = __builtin_amdgcn_rcpf(v[2]);
    r[3] = __builtin_amdgcn_rcpf(v[3]);
    return r;
}

// ---------------------------------------------------------------------------
// FUSED kernel: UGRNN recurrence + FC1 partial GEMM.
// Block = 4 tokens x ALL 64 batches (256 seqs), grid 1024 x 512 threads.
// Phase A: 8 waves x 2 tiles (16 seqs each) run the R5 recurrence math
//   (operand-swapped MFMA, log2e-folded weights, shared-rcp activations).
//   Inputs reg-staged to LDS f16; per-wave work identical to the R5 kernel.
//   Ends writing h to hs[batch][k_local] LDS panel.
// Phase B: FC1 partial for this block's 64 K-rows: M=64 batches, N=256,
//   K=64. A from hs (ds_read_b128), B DIRECT from global W1 (each W1 value
//   read exactly once chip-wide; no W1 LDS). Partials f16, b-major.
// A tiny W1 prefetch at phase-A start pulls the block's 64 KB W1 chunk
// toward L2/L3 so the W1 stream overlaps the recurrence compute.
// Layouts (verified R1): MFMA16 B frag [k=4q+i][n=t16] == C/D [4q+r][t16];
// MFMA32 A [m=t16][k=8q+i], B [k=8q+i][n=t16], D [m=4q+r][n=t16].
// ---------------------------------------------------------------------------
__global__
__attribute__((amdgpu_flat_work_group_size(512, 512), amdgpu_waves_per_eu(6, 8)))
void ugrnn_fc1(
    const float* __restrict__ inputs,
    const float* __restrict__ Wn, const float* __restrict__ Wg,
    const float* __restrict__ Ug, const float* __restrict__ bg,
    const float* __restrict__ Wc, const float* __restrict__ Uc,
    const float* __restrict__ bc, const float* __restrict__ We,
    const float* __restrict__ be, const float* __restrict__ W1,
    _Float16* __restrict__ partials)
{
    __shared__ _Float16 neigh[256][40];   // 20.5 KB, pad->2-way banks, 16B rows
    __shared__ float    he[256][2];       // 2 KB (h0, e0)
    __shared__ _Float16 hs[64][72];       // 9.2 KB h panel [batch][k_local]

    const int tid  = threadIdx.x;
    const int wave = tid >> 6;            // 0..7
    const int lane = tid & 63;
    const int t16  = lane & 15;
    const int q    = lane >> 4;
    const int bk   = blockIdx.x;          // token-chunk: tokens bk*4..bk*4+3
    const int n0   = bk << 2;

    // ---- input staging: thread -> (seq = tid/2, half = tid&1), 17 dwords ---
    {
        const int ss = tid >> 1;
        const int hf = tid & 1;
        const int sb = ss & 63;
        const int sn = ss >> 6;
        const float* row = inputs + ((size_t)sb * 4096 + (n0 + sn)) * 34 + hf * 17;
        float d[17];
#pragma unroll
        for (int i = 0; i < 17; ++i) d[i] = row[i];
        if (hf == 0) he[ss][0] = d[0];
        else         he[ss][1] = d[16];
        const int c0 = hf << 4;
#pragma unroll
        for (int j = 0; j < 16; j += 2) {
            float a = (hf == 0) ? d[1 + j] : d[j];
            float b = (hf == 0) ? d[2 + j] : d[j + 1];
            *(fp16x2*)&neigh[ss][c0 + j] = __builtin_amdgcn_cvt_pkrtz(a, b);
        }
    }

    const float NL2E = -1.44269504f;   // -log2(e)   : sigmoid arg scale
    const float TL2E =  2.88539008f;   // 2*log2(e)  : tanh arg scale

    // weight A-fragments (A[m=t16][k] = W[k][t16]); co-scheduled with staging
    half8_t An;
#pragma unroll
    for (int i = 0; i < 8; ++i)
        An[i] = (_Float16)Wn[(q * 8 + i) * 16 + t16];

    half4_t Awg, Aug, Awc, Auc, Awe;
#pragma unroll
    for (int i = 0; i < 4; ++i) {
        const int k = 4 * q + i;
        Awg[i] = (_Float16)(Wg[k * 16 + t16] * NL2E);
        Aug[i] = (_Float16)(Ug[k * 16 + t16] * NL2E);
        Awc[i] = (_Float16)(Wc[k * 16 + t16] * TL2E);
        Auc[i] = (_Float16)(Uc[k * 16 + t16] * TL2E);
        Awe[i] = (_Float16)(We[k * 16 + t16] * TL2E);
    }
    f32x4 bgC, bcC, beC;
#pragma unroll
    for (int r = 0; r < 4; ++r) {
        bgC[r] = bg[4 * q + r] * NL2E;
        bcC[r] = bc[4 * q + r] * TL2E;
        beC[r] = be[4 * q + r] * TL2E;
    }

    __syncthreads();

    // W1 prefetch: touch the block's 64 KB W1 chunk (2 cachelines/thread);
    // kept alive via asm at kernel end -> no wait on the critical path.
    const float* pfp = W1 + (size_t)bk * 16384 + tid * 32;
    float pf0 = pfp[0], pf1 = pfp[16];

    // ---- phase A: recurrence (R5 math, 2 tiles/wave) ----
    f32x4 m[2], h[2], e[2];
    const f32x4 zc = {0.f, 0.f, 0.f, 0.f};
#pragma unroll
    for (int u2 = 0; u2 < 2; ++u2) {
        const int T = wave * 2 + u2;
        const int s = T * 16 + t16;
        half8_t Bx = *(const half8_t*)&neigh[s][q * 8];   // B[k=8q+i][n=t16]
        m[u2] = MFMA32(An, Bx, zc);
        const float hv = he[s][0];
        const float ev = he[s][1];
        h[u2] = (f32x4){hv, hv, hv, hv};
        e[u2] = (f32x4){ev, ev, ev, ev};
    }

    const f32x4 one = {1.f, 1.f, 1.f, 1.f};

#pragma unroll 1
    for (int step = 0; step < 8; ++step) {
        f32x4 gp[2], cp[2], ep[2];
#pragma unroll
        for (int u2 = 0; u2 < 2; ++u2) {
            const f32x4 x = m[u2] + e[u2];
            half4_t xB = pk4(x);
            half4_t hB = pk4(h[u2]);
            f32x4 g1 = MFMA16(Awg, xB, bgC);
            f32x4 g2 = MFMA16(Aug, hB, zc);
            f32x4 c1 = MFMA16(Awc, xB, bcC);
            f32x4 c2 = MFMA16(Auc, hB, zc);
            gp[u2] = g1 + g2;
            cp[u2] = c1 + c2;
            if (step < 7) ep[u2] = MFMA16(Awe, xB, beC);
        }
#pragma unroll
        for (int u2 = 0; u2 < 2; ++u2) {
            const f32x4 Ae = one + exp2v(gp[u2]);
            const f32x4 Be = one + exp2v(cp[u2]);
            if (step < 7) {
                const f32x4 Ce = one + exp2v(ep[u2]);
                const f32x4 BC = Be * Ce;
                const f32x4 rr = rcpv(Ae * BC);
                const f32x4 gv = rr * BC;
                const f32x4 cv = one - 2.0f * (rr * (Ae * Ce));
                h[u2] = cv + gv * (h[u2] - cv);
                e[u2] = one - 2.0f * (rr * (Ae * Be));
            } else {
                const f32x4 rr = rcpv(Ae * Be);
                const f32x4 gv = rr * Be;
                const f32x4 cv = one - 2.0f * (rr * Ae);
                h[u2] = cv + gv * (h[u2] - cv);
            }
        }
    }

    // write h panel: hs[batch][k_local = n_local*16 + u]
#pragma unroll
    for (int u2 = 0; u2 < 2; ++u2) {
        const int T = wave * 2 + u2;
        *(half4_t*)&hs[(T & 3) * 16 + t16][(T >> 2) * 16 + q * 4] = pk4(h[u2]);
    }
    __syncthreads();

    // ---- phase B: FC1 partial GEMM (M=64, N=256, K=64) ----
    f32x4 acc[4][2];
#pragma unroll
    for (int mt = 0; mt < 4; ++mt)
#pragma unroll
        for (int jt = 0; jt < 2; ++jt)
            acc[mt][jt] = (f32x4){0.f, 0.f, 0.f, 0.f};

    const int j0w = wave * 32;
#pragma unroll
    for (int ks = 0; ks < 2; ++ks) {
        half8_t A[4];                     // A[m=t16][k=8q+i] = hs[m][kloc]
#pragma unroll
        for (int mt = 0; mt < 4; ++mt)
            A[mt] = *(const half8_t*)&hs[mt * 16 + t16][ks * 32 + q * 8];
#pragma unroll
        for (int jt = 0; jt < 2; ++jt) {
            const float* wp = W1
                + (size_t)(bk * 64 + ks * 32 + q * 8) * 256 + j0w + jt * 16 + t16;
            half8_t Bf;                   // B[k=8q+i][n=t16] = W1[k][j]
#pragma unroll
            for (int i = 0; i < 8; ++i)
                Bf[i] = (_Float16)wp[i * 256];
#pragma unroll
            for (int mt = 0; mt < 4; ++mt)
                acc[mt][jt] = MFMA32(A[mt], Bf, acc[mt][jt]);
        }
    }

    // partials layout: [b][1024 chunks][256 j] f16 (b-major for mlp_tail)
#pragma unroll
    for (int mt = 0; mt < 4; ++mt)
#pragma unroll
        for (int jt = 0; jt < 2; ++jt) {
            half4_t hv = pk4(acc[mt][jt]);
#pragma unroll
            for (int r = 0; r < 4; ++r)
                partials[((size_t)(mt * 16 + q * 4 + r) * 1024 + bk) * 256
                         + j0w + jt * 16 + t16] = hv[r];
        }

    asm volatile("" :: "v"(pf0), "v"(pf1));   // keep prefetch alive, no wait
}

// ---------------------------------------------------------------------------
// Kernel 2: fused partial-reduce + bias + tail MLP + softmax.
// 1024 b-major chunks: 16 K-groups x 64 coalesced half4 loads each.
// ---------------------------------------------------------------------------
__global__ __launch_bounds__(1024) void mlp_tail(
    const _Float16* __restrict__ partials, const float* __restrict__ b1,
    const float* __restrict__ W2, const float* __restrict__ b2,
    const float* __restrict__ W3, const float* __restrict__ b3,
    float* __restrict__ out)
{
    __shared__ float x1p[16][256];
    __shared__ float x1s[256];
    __shared__ float x2q[32][33];
    __shared__ float x2s[32];
    __shared__ float lg[2];
    const int b = blockIdx.x, tid = threadIdx.x;
    const int kg = tid >> 6, l64 = tid & 63;
    const int j0 = l64 * 4;

    const _Float16* p = partials + (size_t)b * 262144
                      + (size_t)(kg * 64) * 256 + j0;
    float s0 = 0.f, s1 = 0.f, s2 = 0.f, s3 = 0.f;
#pragma unroll 8
    for (int k = 0; k < 64; ++k) {
        half4_t v = *(const half4_t*)(p + (size_t)k * 256);
        s0 += (float)v[0]; s1 += (float)v[1]; s2 += (float)v[2]; s3 += (float)v[3];
    }
    x1p[kg][j0 + 0] = s0;
    x1p[kg][j0 + 1] = s1;
    x1p[kg][j0 + 2] = s2;
    x1p[kg][j0 + 3] = s3;
    __syncthreads();

    if (tid < 256) {
        float t = b1[tid];
#pragma unroll
        for (int g = 0; g < 16; ++g) t += x1p[g][tid];
        x1s[tid] = fmaxf(t, 0.f);
    }
    __syncthreads();

    const int j2 = tid & 31, g2 = tid >> 5;
    float s = 0.f;
#pragma unroll
    for (int k = g2 * 8; k < g2 * 8 + 8; ++k) s += x1s[k] * W2[k * 32 + j2];
    x2q[g2][j2] = s;
    __syncthreads();
    if (tid < 32) {
        float t = b2[tid];
#pragma unroll
        for (int g = 0; g < 32; ++g) t += x2q[g][tid];
        x2s[tid] = fmaxf(t, 0.f);
    }
    __syncthreads();
    if (tid < 2) {
        float t = b3[tid];
#pragma unroll
        for (int k = 0; k < 32; ++k) t += x2s[k] * W3[k * 2 + tid];
        lg[tid] = t;
    }
    __syncthreads();
    if (tid == 0) {
        float mx = fmaxf(lg[0], lg[1]);
        float e0 = __expf(lg[0] - mx), e1 = __expf(lg[1] - mx);
        float inv = 1.0f / (e0 + e1);
        out[b * 2 + 0] = e0 * inv;
        out[b * 2 + 1] = e1 * inv;
    }
}

// ---------------------------------------------------------------------------
extern "C" void kernel_launch(void* const* d_in, const int* in_sizes, int n_in,
                              void* d_out, int out_size, void* d_ws, size_t ws_size,
                              hipStream_t stream) {
    const float* inputs = (const float*)d_in[0];
    const float* Wn = (const float*)d_in[1];
    const float* Wg = (const float*)d_in[2];
    const float* Ug = (const float*)d_in[3];
    const float* bg = (const float*)d_in[4];
    const float* Wc = (const float*)d_in[5];
    const float* Uc = (const float*)d_in[6];
    const float* bc = (const float*)d_in[7];
    const float* We = (const float*)d_in[8];
    const float* be = (const float*)d_in[9];
    const float* W1 = (const float*)d_in[10];
    const float* b1 = (const float*)d_in[11];
    const float* W2 = (const float*)d_in[12];
    const float* b2 = (const float*)d_in[13];
    const float* W3 = (const float*)d_in[14];
    const float* b3 = (const float*)d_in[15];
    float* out = (float*)d_out;

    // ws: partials f16 [64][1024][256] = 32 MB
    _Float16* partials = (_Float16*)d_ws;

    ugrnn_fc1<<<1024, 512, 0, stream>>>(inputs, Wn, Wg, Ug, bg, Wc, Uc, bc,
                                        We, be, W1, partials);
    mlp_tail<<<64, 1024, 0, stream>>>(partials, b1, W2, b2, W3, b3, out);
}

// Round 7
// 231.888 us; speedup vs baseline: 1.0649x; 1.0649x over previous
//
#include <hip/hip_runtime.h>

typedef _Float16 half8_t __attribute__((ext_vector_type(8)));
typedef _Float16 half4_t __attribute__((ext_vector_type(4)));
typedef __fp16   fp16x2  __attribute__((ext_vector_type(2)));
typedef float    f32x4  __attribute__((ext_vector_type(4)));
typedef float    f32x4u __attribute__((ext_vector_type(4), aligned(4)));

#define MFMA32(a, b, c) __builtin_amdgcn_mfma_f32_16x16x32_f16((a), (b), (c), 0, 0, 0)
#define MFMA16(a, b, c) __builtin_amdgcn_mfma_f32_16x16x16f16((a), (b), (c), 0, 0, 0)

// async global->LDS DMA: LDS dst = wave-uniform base + lane*width (HW rule);
// global src carries the per-lane offset explicitly.
__device__ __forceinline__ void load_lds16(const void* g, void* l) {
    __builtin_amdgcn_global_load_lds(
        (const __attribute__((address_space(1))) unsigned int*)g,
        (__attribute__((address_space(3))) unsigned int*)l, 16, 0, 0);
}

// 4x f32 -> half4 via 2x v_cvt_pkrtz_f16_f32
__device__ __forceinline__ half4_t pk4(f32x4 v) {
    fp16x2 lo = __builtin_amdgcn_cvt_pkrtz(v[0], v[1]);
    fp16x2 hi = __builtin_amdgcn_cvt_pkrtz(v[2], v[3]);
    half4_t r;
    r[0] = (_Float16)lo[0]; r[1] = (_Float16)lo[1];
    r[2] = (_Float16)hi[0]; r[3] = (_Float16)hi[1];
    return r;
}
__device__ __forceinline__ f32x4 exp2v(f32x4 v) {
    f32x4 r;
    r[0] = __builtin_amdgcn_exp2f(v[0]);
    r[1] = __builtin_amdgcn_exp2f(v[1]);
    r[2] = __builtin_amdgcn_exp2f(v[2]);
    r[3] = __builtin_amdgcn_exp2f(v[3]);
    return r;
}
__device__ __forceinline__ f32x4 rcpv(f32x4 v) {
    f32x4 r;
    r[0] = __builtin_amdgcn_rcpf(v[0]);
    r[1] = __builtin_amdgcn_rcpf(v[1]);
    r[2] = __builtin_amdgcn_rcpf(v[2]);
    r[3] = __builtin_amdgcn_rcpf(v[3]);
    return r;
}

// ---------------------------------------------------------------------------
// Kernel 1: UGRNN recurrence, operand-swapped MFMA (D^T = W^T X^T).
// R7: ZERO LDS. Occupancy across R0/R1/R3/R5 tracked LDS/block (27.6KB->26%,
// 17.4KB->33%, 34.8KB->24%): blocks/CU was LDS-co-residency-limited, which is
// why three different instruction mixes all measured ~41 us (deps unhidden at
// ~3 waves/SIMD). The LDS only staged the INITIAL fragment transpose; each
// wave's input slice is a contiguous 4.3KB region, so load fragments directly
// from global (4B-aligned vector loads, 32B/lane) and cvt in-reg. Step-loop
// math = R5 (de-chained MFMAs, log2e-folded weights, shared rcp, pk ops).
// Layouts (verified R1): MFMA16 B frag [k=4q+i][n=t16] == C/D [4q+r][t16];
// MFMA32 A [m=t16][k=8q+i], B [k=8q+i][n=t16], D [m=4q+r][n=t16].
// ---------------------------------------------------------------------------
__global__
__attribute__((amdgpu_flat_work_group_size(256, 256), amdgpu_waves_per_eu(6, 8)))
void ugrnn_mfma(
    const float* __restrict__ inputs,
    const float* __restrict__ Wn, const float* __restrict__ Wg,
    const float* __restrict__ Ug, const float* __restrict__ bg,
    const float* __restrict__ Wc, const float* __restrict__ Uc,
    const float* __restrict__ bc, const float* __restrict__ We,
    const float* __restrict__ be, _Float16* __restrict__ h_t)
{
    const int wave = threadIdx.x >> 6;
    const int lane = threadIdx.x & 63;
    const int t16  = lane & 15;
    const int q    = lane >> 4;

    const int pair = blockIdx.x * 4 + wave;    // [0, 8192)
    const int b    = pair >> 7;
    const int n0   = (pair & 127) << 5;

    const float NL2E = -1.44269504f;   // -log2(e)   : sigmoid arg scale
    const float TL2E =  2.88539008f;   // 2*log2(e)  : tanh arg scale

    // ---- direct-from-global fragment loads (once, off the hot loop) ----
    const float* gsrc = inputs + (size_t)pair * 1088;
    f32x4 m[2], h[2], e[2];
    const f32x4 zc = {0.f, 0.f, 0.f, 0.f};

    // weight A-fragments (A[m=t16][k] = W[k][t16]); fly with the input loads
    half8_t An;
#pragma unroll
    for (int i = 0; i < 8; ++i)
        An[i] = (_Float16)Wn[(q * 8 + i) * 16 + t16];

    half4_t Awg, Aug, Awc, Auc, Awe;
#pragma unroll
    for (int i = 0; i < 4; ++i) {
        const int k = 4 * q + i;
        Awg[i] = (_Float16)(Wg[k * 16 + t16] * NL2E);
        Aug[i] = (_Float16)(Ug[k * 16 + t16] * NL2E);
        Awc[i] = (_Float16)(Wc[k * 16 + t16] * TL2E);
        Auc[i] = (_Float16)(Uc[k * 16 + t16] * TL2E);
        Awe[i] = (_Float16)(We[k * 16 + t16] * TL2E);
    }
    f32x4 bgC, bcC, beC;
#pragma unroll
    for (int r = 0; r < 4; ++r) {
        bgC[r] = bg[4 * q + r] * NL2E;
        bcC[r] = bc[4 * q + r] * TL2E;
        beC[r] = be[4 * q + r] * TL2E;
    }

#pragma unroll
    for (int u2 = 0; u2 < 2; ++u2) {
        const float* rp = gsrc + u2 * 544 + t16 * 34;
        // neigh[t16][q*8 .. q*8+7]: 8 contiguous f32 (4B-aligned vec loads)
        f32x4 x0 = *(const f32x4u*)(rp + 1 + q * 8);
        f32x4 x1 = *(const f32x4u*)(rp + 5 + q * 8);
        half8_t Bx;                     // B[k=8q+i][n=t16]
        half4_t blo = pk4(x0), bhi = pk4(x1);
#pragma unroll
        for (int i = 0; i < 4; ++i) { Bx[i] = blo[i]; Bx[4 + i] = bhi[i]; }
        m[u2] = MFMA32(An, Bx, zc);
        const float hv = rp[0];
        const float ev = rp[33];
        h[u2] = (f32x4){hv, hv, hv, hv};
        e[u2] = (f32x4){ev, ev, ev, ev};
    }

    const f32x4 one = {1.f, 1.f, 1.f, 1.f};

#pragma unroll 1
    for (int step = 0; step < 8; ++step) {
        f32x4 gp[2], cp[2], ep[2];
#pragma unroll
        for (int u2 = 0; u2 < 2; ++u2) {
            const f32x4 x = m[u2] + e[u2];
            half4_t xB = pk4(x);
            half4_t hB = pk4(h[u2]);
            // de-chained: independent MFMAs, pk-add the pairs
            f32x4 g1 = MFMA16(Awg, xB, bgC);
            f32x4 g2 = MFMA16(Aug, hB, zc);
            f32x4 c1 = MFMA16(Awc, xB, bcC);
            f32x4 c2 = MFMA16(Auc, hB, zc);
            gp[u2] = g1 + g2;
            cp[u2] = c1 + c2;
            if (step < 7) ep[u2] = MFMA16(Awe, xB, beC);
        }
#pragma unroll
        for (int u2 = 0; u2 < 2; ++u2) {
            const f32x4 Ae = one + exp2v(gp[u2]);
            const f32x4 Be = one + exp2v(cp[u2]);
            if (step < 7) {
                const f32x4 Ce = one + exp2v(ep[u2]);
                const f32x4 BC = Be * Ce;
                const f32x4 rr = rcpv(Ae * BC);
                const f32x4 gv = rr * BC;                  // sigma(gate)
                const f32x4 cv = one - 2.0f * (rr * (Ae * Ce)); // tanh(c)
                h[u2] = cv + gv * (h[u2] - cv);
                e[u2] = one - 2.0f * (rr * (Ae * Be));     // tanh(e)
            } else {
                const f32x4 rr = rcpv(Ae * Be);
                const f32x4 gv = rr * Be;
                const f32x4 cv = one - 2.0f * (rr * Ae);
                h[u2] = cv + gv * (h[u2] - cv);
            }
        }
    }

    // coalesced store: 64 lanes tile 512 B contiguously per u2
#pragma unroll
    for (int u2 = 0; u2 < 2; ++u2)
        *(half4_t*)(h_t + (size_t)b * 65536
                        + (size_t)(n0 + u2 * 16 + t16) * 16 + 4 * q) =
            pk4(h[u2]);
}

// ---------------------------------------------------------------------------
// Kernel 2: FC1 partial GEMM. (R4 form: grid 512, K=128/block, 32-row
// chunks, double-buffered 66 KB LDS; DMA-bound at the W1 streaming floor,
// queue stays full across barriers.)
// ---------------------------------------------------------------------------
__global__
__attribute__((amdgpu_flat_work_group_size(256, 256)))
void fc1_mfma(const _Float16* __restrict__ h_t, const float* __restrict__ W1,
              _Float16* __restrict__ partials)
{
    __shared__ float w1s[2][32][258];          // 66048 B
    const int tid  = threadIdx.x;
    const int wave = tid >> 6;                 // 0..3
    const int lane = tid & 63;
    const int t16  = lane & 15;
    const int q    = lane >> 4;
    const int i0   = blockIdx.x * 128;

    f32x4 acc[4][4];
#pragma unroll
    for (int mt = 0; mt < 4; ++mt)
#pragma unroll
        for (int nt = 0; nt < 4; ++nt)
            acc[mt][nt] = (f32x4){0.f, 0.f, 0.f, 0.f};

    // prologue: DMA chunk 0 (each wave stages 8 rows of 1 KB)
#pragma unroll
    for (int r = 0; r < 8; ++r) {
        int row = wave * 8 + r;
        load_lds16(W1 + (size_t)(i0 + row) * 256 + lane * 4, &w1s[0][row][0]);
    }
    __syncthreads();                           // drains chunk-0 DMA

#pragma unroll 1
    for (int c = 0; c < 4; ++c) {
        const int buf = c & 1;
        const int cb  = i0 + c * 32;

        // A-frags issued first so their latency overlaps the DMA
        half8_t A[4];
#pragma unroll
        for (int mt = 0; mt < 4; ++mt)
            A[mt] = *(const half8_t*)(h_t
                + (size_t)(mt * 16 + t16) * 65536 + cb + q * 8);

        if (c < 3) {
#pragma unroll
            for (int r = 0; r < 8; ++r) {
                int row = wave * 8 + r;
                load_lds16(W1 + (size_t)(cb + 32 + row) * 256 + lane * 4,
                           &w1s[buf ^ 1][row][0]);
            }
        }

#pragma unroll
        for (int nt = 0; nt < 4; ++nt) {
            int j = (wave * 4 + nt) * 16 + t16;
            half8_t Bf;
#pragma unroll
            for (int i = 0; i < 8; ++i)
                Bf[i] = (_Float16)w1s[buf][q * 8 + i][j];
#pragma unroll
            for (int mt = 0; mt < 4; ++mt)
                acc[mt][nt] = MFMA32(A[mt], Bf, acc[mt][nt]);
        }
        __syncthreads();                       // sync + drain next-chunk DMA
    }

    _Float16* pb = partials + (size_t)blockIdx.x * 16384;
#pragma unroll
    for (int mt = 0; mt < 4; ++mt)
#pragma unroll
        for (int nt = 0; nt < 4; ++nt)
#pragma unroll
            for (int r = 0; r < 4; ++r)
                pb[(mt * 16 + 4 * q + r) * 256 + (wave * 4 + nt) * 16 + t16] =
                    (_Float16)acc[mt][nt][r];
}

// ---------------------------------------------------------------------------
// Kernel 3: fused partial-reduce + bias + tail MLP + softmax.
// 512 partials: 16 K-groups x 32 coalesced half4 loads each.
// ---------------------------------------------------------------------------
__global__ __launch_bounds__(1024) void mlp_tail(
    const _Float16* __restrict__ partials, const float* __restrict__ b1,
    const float* __restrict__ W2, const float* __restrict__ b2,
    const float* __restrict__ W3, const float* __restrict__ b3,
    float* __restrict__ out)
{
    __shared__ float x1p[16][256];
    __shared__ float x1s[256];
    __shared__ float x2q[32][33];
    __shared__ float x2s[32];
    __shared__ float lg[2];
    const int b = blockIdx.x, tid = threadIdx.x;
    const int kg = tid >> 6, l64 = tid & 63;
    const int j0 = l64 * 4;

    const _Float16* p = partials + (size_t)(kg * 32) * 16384 + (size_t)b * 256 + j0;
    float s0 = 0.f, s1 = 0.f, s2 = 0.f, s3 = 0.f;
#pragma unroll
    for (int k = 0; k < 32; ++k) {
        half4_t v = *(const half4_t*)(p + (size_t)k * 16384);
        s0 += (float)v[0]; s1 += (float)v[1]; s2 += (float)v[2]; s3 += (float)v[3];
    }
    x1p[kg][j0 + 0] = s0;
    x1p[kg][j0 + 1] = s1;
    x1p[kg][j0 + 2] = s2;
    x1p[kg][j0 + 3] = s3;
    __syncthreads();

    if (tid < 256) {
        float t = b1[tid];
#pragma unroll
        for (int g = 0; g < 16; ++g) t += x1p[g][tid];
        x1s[tid] = fmaxf(t, 0.f);
    }
    __syncthreads();

    const int j2 = tid & 31, g2 = tid >> 5;
    float s = 0.f;
#pragma unroll
    for (int k = g2 * 8; k < g2 * 8 + 8; ++k) s += x1s[k] * W2[k * 32 + j2];
    x2q[g2][j2] = s;
    __syncthreads();
    if (tid < 32) {
        float t = b2[tid];
#pragma unroll
        for (int g = 0; g < 32; ++g) t += x2q[g][tid];
        x2s[tid] = fmaxf(t, 0.f);
    }
    __syncthreads();
    if (tid < 2) {
        float t = b3[tid];
#pragma unroll
        for (int k = 0; k < 32; ++k) t += x2s[k] * W3[k * 2 + tid];
        lg[tid] = t;
    }
    __syncthreads();
    if (tid == 0) {
        float mx = fmaxf(lg[0], lg[1]);
        float e0 = __expf(lg[0] - mx), e1 = __expf(lg[1] - mx);
        float inv = 1.0f / (e0 + e1);
        out[b * 2 + 0] = e0 * inv;
        out[b * 2 + 1] = e1 * inv;
    }
}

// ---------------------------------------------------------------------------
extern "C" void kernel_launch(void* const* d_in, const int* in_sizes, int n_in,
                              void* d_out, int out_size, void* d_ws, size_t ws_size,
                              hipStream_t stream) {
    const float* inputs = (const float*)d_in[0];
    const float* Wn = (const float*)d_in[1];
    const float* Wg = (const float*)d_in[2];
    const float* Ug = (const float*)d_in[3];
    const float* bg = (const float*)d_in[4];
    const float* Wc = (const float*)d_in[5];
    const float* Uc = (const float*)d_in[6];
    const float* bc = (const float*)d_in[7];
    const float* We = (const float*)d_in[8];
    const float* be = (const float*)d_in[9];
    const float* W1 = (const float*)d_in[10];
    const float* b1 = (const float*)d_in[11];
    const float* W2 = (const float*)d_in[12];
    const float* b2 = (const float*)d_in[13];
    const float* W3 = (const float*)d_in[14];
    const float* b3 = (const float*)d_in[15];
    float* out = (float*)d_out;

    // ws: h_t f16 [64][65536] = 8 MB; partials f16 [512][64][256] = 16 MB
    _Float16* h_t      = (_Float16*)d_ws;
    _Float16* partials = (_Float16*)((char*)d_ws + (size_t)64 * 65536 * 2);

    ugrnn_mfma<<<2048, 256, 0, stream>>>(inputs, Wn, Wg, Ug, bg, Wc, Uc, bc,
                                         We, be, h_t);
    fc1_mfma<<<512, 256, 0, stream>>>(h_t, W1, partials);
    mlp_tail<<<64, 1024, 0, stream>>>(partials, b1, W2, b2, W3, b3, out);
}

// Round 8
// 181.242 us; speedup vs baseline: 1.3624x; 1.2794x over previous
//
#include <hip/hip_runtime.h>

typedef _Float16 half8_t __attribute__((ext_vector_type(8)));
typedef _Float16 half4_t __attribute__((ext_vector_type(4)));
typedef __fp16   fp16x2  __attribute__((ext_vector_type(2)));
typedef float    f32x4  __attribute__((ext_vector_type(4)));
typedef float    f32x4u __attribute__((ext_vector_type(4), aligned(4)));

#define MFMA32(a, b, c) __builtin_amdgcn_mfma_f32_16x16x32_f16((a), (b), (c), 0, 0, 0)
#define MFMA16(a, b, c) __builtin_amdgcn_mfma_f32_16x16x16f16((a), (b), (c), 0, 0, 0)

// async global->LDS DMA: LDS dst = wave-uniform base + lane*width (HW rule);
// global src carries the per-lane offset explicitly.
__device__ __forceinline__ void load_lds16(const void* g, void* l) {
    __builtin_amdgcn_global_load_lds(
        (const __attribute__((address_space(1))) unsigned int*)g,
        (__attribute__((address_space(3))) unsigned int*)l, 16, 0, 0);
}

// 4x f32 -> half4 via 2x v_cvt_pkrtz_f16_f32
__device__ __forceinline__ half4_t pk4(f32x4 v) {
    fp16x2 lo = __builtin_amdgcn_cvt_pkrtz(v[0], v[1]);
    fp16x2 hi = __builtin_amdgcn_cvt_pkrtz(v[2], v[3]);
    half4_t r;
    r[0] = (_Float16)lo[0]; r[1] = (_Float16)lo[1];
    r[2] = (_Float16)hi[0]; r[3] = (_Float16)hi[1];
    return r;
}
__device__ __forceinline__ f32x4 exp2v(f32x4 v) {
    f32x4 r;
    r[0] = __builtin_amdgcn_exp2f(v[0]);
    r[1] = __builtin_amdgcn_exp2f(v[1]);
    r[2] = __builtin_amdgcn_exp2f(v[2]);
    r[3] = __builtin_amdgcn_exp2f(v[3]);
    return r;
}
__device__ __forceinline__ f32x4 rcpv(f32x4 v) {
    f32x4 r;
    r[0] = __builtin_amdgcn_rcpf(v[0]);
    r[1] = __builtin_amdgcn_rcpf(v[1]);
    r[2] = __builtin_amdgcn_rcpf(v[2]);
    r[3] = __builtin_amdgcn_rcpf(v[3]);
    return r;
}

// ---------------------------------------------------------------------------
// Kernel 1: UGRNN recurrence, operand-swapped MFMA (D^T = W^T X^T).
// R8: R7's zero-LDS structure WITHOUT the waves_per_eu cap. R7's counters:
// waves_per_eu(6,8) squeezed VGPR to 40 -> hot-loop scratch spills ->
// WRITE_SIZE 53 MB (vs 8 MB output) -> HBM-traffic-bound at exactly
// 95 MB / 1.19 TB/s = 80 us. Same math fit in 64 VGPR spill-free in R5.
// Zero-LDS DID raise occupancy (33 -> 49%): keep it, free the allocator.
//  - fragment/initial-state loads direct from global (contiguous 4.3 KB
//    per-wave slice, 32 B/lane vector loads), cvt in-reg
//  - step loop: de-chained MFMAs, log2e-folded weights (bare v_exp_f32),
//    shared rcp per 3 sigmoids, f32x4 algebra -> v_pk_* packed fp32
// Layouts (verified R1): MFMA16 B frag [k=4q+i][n=t16] == C/D [4q+r][t16];
// MFMA32 A [m=t16][k=8q+i], B [k=8q+i][n=t16], D [m=4q+r][n=t16].
// ---------------------------------------------------------------------------
__global__
__attribute__((amdgpu_flat_work_group_size(256, 256)))
void ugrnn_mfma(
    const float* __restrict__ inputs,
    const float* __restrict__ Wn, const float* __restrict__ Wg,
    const float* __restrict__ Ug, const float* __restrict__ bg,
    const float* __restrict__ Wc, const float* __restrict__ Uc,
    const float* __restrict__ bc, const float* __restrict__ We,
    const float* __restrict__ be, _Float16* __restrict__ h_t)
{
    const int wave = threadIdx.x >> 6;
    const int lane = threadIdx.x & 63;
    const int t16  = lane & 15;
    const int q    = lane >> 4;

    const int pair = blockIdx.x * 4 + wave;    // [0, 8192)
    const int b    = pair >> 7;
    const int n0   = (pair & 127) << 5;

    const float NL2E = -1.44269504f;   // -log2(e)   : sigmoid arg scale
    const float TL2E =  2.88539008f;   // 2*log2(e)  : tanh arg scale

    // ---- direct-from-global fragment loads (once, off the hot loop) ----
    const float* gsrc = inputs + (size_t)pair * 1088;
    f32x4 m[2], h[2], e[2];
    const f32x4 zc = {0.f, 0.f, 0.f, 0.f};

    // weight A-fragments (A[m=t16][k] = W[k][t16]); fly with the input loads
    half8_t An;
#pragma unroll
    for (int i = 0; i < 8; ++i)
        An[i] = (_Float16)Wn[(q * 8 + i) * 16 + t16];

    half4_t Awg, Aug, Awc, Auc, Awe;
#pragma unroll
    for (int i = 0; i < 4; ++i) {
        const int k = 4 * q + i;
        Awg[i] = (_Float16)(Wg[k * 16 + t16] * NL2E);
        Aug[i] = (_Float16)(Ug[k * 16 + t16] * NL2E);
        Awc[i] = (_Float16)(Wc[k * 16 + t16] * TL2E);
        Auc[i] = (_Float16)(Uc[k * 16 + t16] * TL2E);
        Awe[i] = (_Float16)(We[k * 16 + t16] * TL2E);
    }
    f32x4 bgC, bcC, beC;
#pragma unroll
    for (int r = 0; r < 4; ++r) {
        bgC[r] = bg[4 * q + r] * NL2E;
        bcC[r] = bc[4 * q + r] * TL2E;
        beC[r] = be[4 * q + r] * TL2E;
    }

#pragma unroll
    for (int u2 = 0; u2 < 2; ++u2) {
        const float* rp = gsrc + u2 * 544 + t16 * 34;
        // neigh[t16][q*8 .. q*8+7]: 8 contiguous f32 (4B-aligned vec loads)
        f32x4 x0 = *(const f32x4u*)(rp + 1 + q * 8);
        f32x4 x1 = *(const f32x4u*)(rp + 5 + q * 8);
        half8_t Bx;                     // B[k=8q+i][n=t16]
        half4_t blo = pk4(x0), bhi = pk4(x1);
#pragma unroll
        for (int i = 0; i < 4; ++i) { Bx[i] = blo[i]; Bx[4 + i] = bhi[i]; }
        m[u2] = MFMA32(An, Bx, zc);
        const float hv = rp[0];
        const float ev = rp[33];
        h[u2] = (f32x4){hv, hv, hv, hv};
        e[u2] = (f32x4){ev, ev, ev, ev};
    }

    const f32x4 one = {1.f, 1.f, 1.f, 1.f};

#pragma unroll 1
    for (int step = 0; step < 8; ++step) {
        f32x4 gp[2], cp[2], ep[2];
#pragma unroll
        for (int u2 = 0; u2 < 2; ++u2) {
            const f32x4 x = m[u2] + e[u2];
            half4_t xB = pk4(x);
            half4_t hB = pk4(h[u2]);
            // de-chained: independent MFMAs, pk-add the pairs
            f32x4 g1 = MFMA16(Awg, xB, bgC);
            f32x4 g2 = MFMA16(Aug, hB, zc);
            f32x4 c1 = MFMA16(Awc, xB, bcC);
            f32x4 c2 = MFMA16(Auc, hB, zc);
            gp[u2] = g1 + g2;
            cp[u2] = c1 + c2;
            if (step < 7) ep[u2] = MFMA16(Awe, xB, beC);
        }
#pragma unroll
        for (int u2 = 0; u2 < 2; ++u2) {
            const f32x4 Ae = one + exp2v(gp[u2]);
            const f32x4 Be = one + exp2v(cp[u2]);
            if (step < 7) {
                const f32x4 Ce = one + exp2v(ep[u2]);
                const f32x4 BC = Be * Ce;
                const f32x4 rr = rcpv(Ae * BC);
                const f32x4 gv = rr * BC;                  // sigma(gate)
                const f32x4 cv = one - 2.0f * (rr * (Ae * Ce)); // tanh(c)
                h[u2] = cv + gv * (h[u2] - cv);
                e[u2] = one - 2.0f * (rr * (Ae * Be));     // tanh(e)
            } else {
                const f32x4 rr = rcpv(Ae * Be);
                const f32x4 gv = rr * Be;
                const f32x4 cv = one - 2.0f * (rr * Ae);
                h[u2] = cv + gv * (h[u2] - cv);
            }
        }
    }

    // coalesced store: 64 lanes tile 512 B contiguously per u2
#pragma unroll
    for (int u2 = 0; u2 < 2; ++u2)
        *(half4_t*)(h_t + (size_t)b * 65536
                        + (size_t)(n0 + u2 * 16 + t16) * 16 + 4 * q) =
            pk4(h[u2]);
}

// ---------------------------------------------------------------------------
// Kernel 2: FC1 partial GEMM. (R4 form: grid 512, K=128/block, 32-row
// chunks, double-buffered 66 KB LDS; DMA-bound at the W1 streaming floor,
// queue stays full across barriers.)
// ---------------------------------------------------------------------------
__global__
__attribute__((amdgpu_flat_work_group_size(256, 256)))
void fc1_mfma(const _Float16* __restrict__ h_t, const float* __restrict__ W1,
              _Float16* __restrict__ partials)
{
    __shared__ float w1s[2][32][258];          // 66048 B
    const int tid  = threadIdx.x;
    const int wave = tid >> 6;                 // 0..3
    const int lane = tid & 63;
    const int t16  = lane & 15;
    const int q    = lane >> 4;
    const int i0   = blockIdx.x * 128;

    f32x4 acc[4][4];
#pragma unroll
    for (int mt = 0; mt < 4; ++mt)
#pragma unroll
        for (int nt = 0; nt < 4; ++nt)
            acc[mt][nt] = (f32x4){0.f, 0.f, 0.f, 0.f};

    // prologue: DMA chunk 0 (each wave stages 8 rows of 1 KB)
#pragma unroll
    for (int r = 0; r < 8; ++r) {
        int row = wave * 8 + r;
        load_lds16(W1 + (size_t)(i0 + row) * 256 + lane * 4, &w1s[0][row][0]);
    }
    __syncthreads();                           // drains chunk-0 DMA

#pragma unroll 1
    for (int c = 0; c < 4; ++c) {
        const int buf = c & 1;
        const int cb  = i0 + c * 32;

        // A-frags issued first so their latency overlaps the DMA
        half8_t A[4];
#pragma unroll
        for (int mt = 0; mt < 4; ++mt)
            A[mt] = *(const half8_t*)(h_t
                + (size_t)(mt * 16 + t16) * 65536 + cb + q * 8);

        if (c < 3) {
#pragma unroll
            for (int r = 0; r < 8; ++r) {
                int row = wave * 8 + r;
                load_lds16(W1 + (size_t)(cb + 32 + row) * 256 + lane * 4,
                           &w1s[buf ^ 1][row][0]);
            }
        }

#pragma unroll
        for (int nt = 0; nt < 4; ++nt) {
            int j = (wave * 4 + nt) * 16 + t16;
            half8_t Bf;
#pragma unroll
            for (int i = 0; i < 8; ++i)
                Bf[i] = (_Float16)w1s[buf][q * 8 + i][j];
#pragma unroll
            for (int mt = 0; mt < 4; ++mt)
                acc[mt][nt] = MFMA32(A[mt], Bf, acc[mt][nt]);
        }
        __syncthreads();                       // sync + drain next-chunk DMA
    }

    _Float16* pb = partials + (size_t)blockIdx.x * 16384;
#pragma unroll
    for (int mt = 0; mt < 4; ++mt)
#pragma unroll
        for (int nt = 0; nt < 4; ++nt)
#pragma unroll
            for (int r = 0; r < 4; ++r)
                pb[(mt * 16 + 4 * q + r) * 256 + (wave * 4 + nt) * 16 + t16] =
                    (_Float16)acc[mt][nt][r];
}

// ---------------------------------------------------------------------------
// Kernel 3: fused partial-reduce + bias + tail MLP + softmax.
// 512 partials: 16 K-groups x 32 coalesced half4 loads each.
// ---------------------------------------------------------------------------
__global__ __launch_bounds__(1024) void mlp_tail(
    const _Float16* __restrict__ partials, const float* __restrict__ b1,
    const float* __restrict__ W2, const float* __restrict__ b2,
    const float* __restrict__ W3, const float* __restrict__ b3,
    float* __restrict__ out)
{
    __shared__ float x1p[16][256];
    __shared__ float x1s[256];
    __shared__ float x2q[32][33];
    __shared__ float x2s[32];
    __shared__ float lg[2];
    const int b = blockIdx.x, tid = threadIdx.x;
    const int kg = tid >> 6, l64 = tid & 63;
    const int j0 = l64 * 4;

    const _Float16* p = partials + (size_t)(kg * 32) * 16384 + (size_t)b * 256 + j0;
    float s0 = 0.f, s1 = 0.f, s2 = 0.f, s3 = 0.f;
#pragma unroll
    for (int k = 0; k < 32; ++k) {
        half4_t v = *(const half4_t*)(p + (size_t)k * 16384);
        s0 += (float)v[0]; s1 += (float)v[1]; s2 += (float)v[2]; s3 += (float)v[3];
    }
    x1p[kg][j0 + 0] = s0;
    x1p[kg][j0 + 1] = s1;
    x1p[kg][j0 + 2] = s2;
    x1p[kg][j0 + 3] = s3;
    __syncthreads();

    if (tid < 256) {
        float t = b1[tid];
#pragma unroll
        for (int g = 0; g < 16; ++g) t += x1p[g][tid];
        x1s[tid] = fmaxf(t, 0.f);
    }
    __syncthreads();

    const int j2 = tid & 31, g2 = tid >> 5;
    float s = 0.f;
#pragma unroll
    for (int k = g2 * 8; k < g2 * 8 + 8; ++k) s += x1s[k] * W2[k * 32 + j2];
    x2q[g2][j2] = s;
    __syncthreads();
    if (tid < 32) {
        float t = b2[tid];
#pragma unroll
        for (int g = 0; g < 32; ++g) t += x2q[g][tid];
        x2s[tid] = fmaxf(t, 0.f);
    }
    __syncthreads();
    if (tid < 2) {
        float t = b3[tid];
#pragma unroll
        for (int k = 0; k < 32; ++k) t += x2s[k] * W3[k * 2 + tid];
        lg[tid] = t;
    }
    __syncthreads();
    if (tid == 0) {
        float mx = fmaxf(lg[0], lg[1]);
        float e0 = __expf(lg[0] - mx), e1 = __expf(lg[1] - mx);
        float inv = 1.0f / (e0 + e1);
        out[b * 2 + 0] = e0 * inv;
        out[b * 2 + 1] = e1 * inv;
    }
}

// ---------------------------------------------------------------------------
extern "C" void kernel_launch(void* const* d_in, const int* in_sizes, int n_in,
                              void* d_out, int out_size, void* d_ws, size_t ws_size,
                              hipStream_t stream) {
    const float* inputs = (const float*)d_in[0];
    const float* Wn = (const float*)d_in[1];
    const float* Wg = (const float*)d_in[2];
    const float* Ug = (const float*)d_in[3];
    const float* bg = (const float*)d_in[4];
    const float* Wc = (const float*)d_in[5];
    const float* Uc = (const float*)d_in[6];
    const float* bc = (const float*)d_in[7];
    const float* We = (const float*)d_in[8];
    const float* be = (const float*)d_in[9];
    const float* W1 = (const float*)d_in[10];
    const float* b1 = (const float*)d_in[11];
    const float* W2 = (const float*)d_in[12];
    const float* b2 = (const float*)d_in[13];
    const float* W3 = (const float*)d_in[14];
    const float* b3 = (const float*)d_in[15];
    float* out = (float*)d_out;

    // ws: h_t f16 [64][65536] = 8 MB; partials f16 [512][64][256] = 16 MB
    _Float16* h_t      = (_Float16*)d_ws;
    _Float16* partials = (_Float16*)((char*)d_ws + (size_t)64 * 65536 * 2);

    ugrnn_mfma<<<2048, 256, 0, stream>>>(inputs, Wn, Wg, Ug, bg, Wc, Uc, bc,
                                         We, be, h_t);
    fc1_mfma<<<512, 256, 0, stream>>>(h_t, W1, partials);
    mlp_tail<<<64, 1024, 0, stream>>>(partials, b1, W2, b2, W3, b3, out);
}

// Round 9
// 178.501 us; speedup vs baseline: 1.3834x; 1.0154x over previous
//
#include <hip/hip_runtime.h>

typedef _Float16 half8_t __attribute__((ext_vector_type(8)));
typedef _Float16 half4_t __attribute__((ext_vector_type(4)));
typedef __fp16   fp16x2  __attribute__((ext_vector_type(2)));
typedef float    f32x4  __attribute__((ext_vector_type(4)));
typedef float    f32x4u __attribute__((ext_vector_type(4), aligned(4)));

#define MFMA32(a, b, c) __builtin_amdgcn_mfma_f32_16x16x32_f16((a), (b), (c), 0, 0, 0)
#define MFMA16(a, b, c) __builtin_amdgcn_mfma_f32_16x16x16f16((a), (b), (c), 0, 0, 0)

// async global->LDS DMA: LDS dst = wave-uniform base + lane*width (HW rule);
// global src carries the per-lane offset explicitly.
__device__ __forceinline__ void load_lds16(const void* g, void* l) {
    __builtin_amdgcn_global_load_lds(
        (const __attribute__((address_space(1))) unsigned int*)g,
        (__attribute__((address_space(3))) unsigned int*)l, 16, 0, 0);
}

// 4x f32 -> half4: two v_cvt_pkrtz into an adjacent VGPR pair (union pun,
// no element-insert movs)
__device__ __forceinline__ half4_t pk4(f32x4 v) {
    union { fp16x2 h2[2]; half4_t h4; } u;
    u.h2[0] = __builtin_amdgcn_cvt_pkrtz(v[0], v[1]);
    u.h2[1] = __builtin_amdgcn_cvt_pkrtz(v[2], v[3]);
    return u.h4;
}
__device__ __forceinline__ f32x4 exp2v(f32x4 v) {
    f32x4 r;
    r[0] = __builtin_amdgcn_exp2f(v[0]);
    r[1] = __builtin_amdgcn_exp2f(v[1]);
    r[2] = __builtin_amdgcn_exp2f(v[2]);
    r[3] = __builtin_amdgcn_exp2f(v[3]);
    return r;
}
__device__ __forceinline__ f32x4 rcpv(f32x4 v) {
    f32x4 r;
    r[0] = __builtin_amdgcn_rcpf(v[0]);
    r[1] = __builtin_amdgcn_rcpf(v[1]);
    r[2] = __builtin_amdgcn_rcpf(v[2]);
    r[3] = __builtin_amdgcn_rcpf(v[3]);
    return r;
}

// ---------------------------------------------------------------------------
// Kernel 1: UGRNN recurrence, operand-swapped MFMA (D^T = W^T X^T).
// R9: instruction-count surgery (kernel is SIMD issue-slot bound: R1's and
// R5's different mixes both ~41 us; latency/trans/HBM ruled out by rounds
// R1-R8). Math identical to R5/R8:
//  - gate MFMAs RE-chained via C operand (latency is free when issue-bound;
//    saves the 4 pk-adds/tile/step of de-chaining)
//  - e-register eliminated: x_next = m1 - 2*(rr*(Ae*Be)), m1 = m+1 hoisted
//    (m loop-invariant) -- saves the x=m+e add each step
//  - pk4 via union pun -> bare v_cvt_pkrtz pair, no insert movs
//  - zero LDS, direct-from-global fragment loads, no waves_per_eu cap
// Layouts (verified R1): MFMA16 B frag [k=4q+i][n=t16] == C/D [4q+r][t16];
// MFMA32 A [m=t16][k=8q+i], B [k=8q+i][n=t16], D [m=4q+r][n=t16].
// ---------------------------------------------------------------------------
__global__
__attribute__((amdgpu_flat_work_group_size(256, 256)))
void ugrnn_mfma(
    const float* __restrict__ inputs,
    const float* __restrict__ Wn, const float* __restrict__ Wg,
    const float* __restrict__ Ug, const float* __restrict__ bg,
    const float* __restrict__ Wc, const float* __restrict__ Uc,
    const float* __restrict__ bc, const float* __restrict__ We,
    const float* __restrict__ be, _Float16* __restrict__ h_t)
{
    const int wave = threadIdx.x >> 6;
    const int lane = threadIdx.x & 63;
    const int t16  = lane & 15;
    const int q    = lane >> 4;

    const int pair = blockIdx.x * 4 + wave;    // [0, 8192)
    const int b    = pair >> 7;
    const int n0   = (pair & 127) << 5;

    const float NL2E = -1.44269504f;   // -log2(e)   : sigmoid arg scale
    const float TL2E =  2.88539008f;   // 2*log2(e)  : tanh arg scale

    // ---- direct-from-global fragment loads (once, off the hot loop) ----
    const float* gsrc = inputs + (size_t)pair * 1088;
    const f32x4 zc  = {0.f, 0.f, 0.f, 0.f};
    const f32x4 one = {1.f, 1.f, 1.f, 1.f};

    // weight A-fragments (A[m=t16][k] = W[k][t16]); fly with the input loads
    half8_t An;
#pragma unroll
    for (int i = 0; i < 8; ++i)
        An[i] = (_Float16)Wn[(q * 8 + i) * 16 + t16];

    half4_t Awg, Aug, Awc, Auc, Awe;
#pragma unroll
    for (int i = 0; i < 4; ++i) {
        const int k = 4 * q + i;
        Awg[i] = (_Float16)(Wg[k * 16 + t16] * NL2E);
        Aug[i] = (_Float16)(Ug[k * 16 + t16] * NL2E);
        Awc[i] = (_Float16)(Wc[k * 16 + t16] * TL2E);
        Auc[i] = (_Float16)(Uc[k * 16 + t16] * TL2E);
        Awe[i] = (_Float16)(We[k * 16 + t16] * TL2E);
    }
    f32x4 bgC, bcC, beC;
#pragma unroll
    for (int r = 0; r < 4; ++r) {
        bgC[r] = bg[4 * q + r] * NL2E;
        bcC[r] = bc[4 * q + r] * TL2E;
        beC[r] = be[4 * q + r] * TL2E;
    }

    f32x4 m1[2], h[2], x[2];
#pragma unroll
    for (int u2 = 0; u2 < 2; ++u2) {
        const float* rp = gsrc + u2 * 544 + t16 * 34;
        // neigh[t16][q*8 .. q*8+7]: 8 contiguous f32 (4B-aligned vec loads)
        f32x4 x0 = *(const f32x4u*)(rp + 1 + q * 8);
        f32x4 x1 = *(const f32x4u*)(rp + 5 + q * 8);
        union { half4_t h4[2]; half8_t h8; } bx;
        bx.h4[0] = pk4(x0);
        bx.h4[1] = pk4(x1);
        f32x4 m = MFMA32(An, bx.h8, zc);     // B[k=8q+i][n=t16]
        const float hv = rp[0];
        const float ev = rp[33];
        h[u2]  = (f32x4){hv, hv, hv, hv};
        m1[u2] = m + one;                     // hoisted: x_next = m1 - 2*rc
        x[u2]  = m + (f32x4){ev, ev, ev, ev}; // initial x = m + e0
    }

#pragma unroll 1
    for (int step = 0; step < 8; ++step) {
        f32x4 gp[2], cp[2], ep[2];
#pragma unroll
        for (int u2 = 0; u2 < 2; ++u2) {
            half4_t xB = pk4(x[u2]);
            half4_t hB = pk4(h[u2]);
            // chained via C operand: 2 MFMA, zero adds
            gp[u2] = MFMA16(Aug, hB, MFMA16(Awg, xB, bgC));
            cp[u2] = MFMA16(Auc, hB, MFMA16(Awc, xB, bcC));
            if (step < 7) ep[u2] = MFMA16(Awe, xB, beC);
        }
#pragma unroll
        for (int u2 = 0; u2 < 2; ++u2) {
            const f32x4 Ae = one + exp2v(gp[u2]);
            const f32x4 Be = one + exp2v(cp[u2]);
            if (step < 7) {
                const f32x4 Ce = one + exp2v(ep[u2]);
                const f32x4 BC = Be * Ce;
                const f32x4 rr = rcpv(Ae * BC);
                const f32x4 gv = rr * BC;                  // sigma(gate)
                const f32x4 cv = one - 2.0f * (rr * (Ae * Ce)); // tanh(c)
                h[u2] = cv + gv * (h[u2] - cv);
                x[u2] = m1[u2] - 2.0f * (rr * (Ae * Be));  // m + tanh(e-pre)
            } else {
                const f32x4 rr = rcpv(Ae * Be);
                const f32x4 gv = rr * Be;
                const f32x4 cv = one - 2.0f * (rr * Ae);
                h[u2] = cv + gv * (h[u2] - cv);
            }
        }
    }

    // coalesced store: 64 lanes tile 512 B contiguously per u2
#pragma unroll
    for (int u2 = 0; u2 < 2; ++u2)
        *(half4_t*)(h_t + (size_t)b * 65536
                        + (size_t)(n0 + u2 * 16 + t16) * 16 + 4 * q) =
            pk4(h[u2]);
}

// ---------------------------------------------------------------------------
// Kernel 2: FC1 partial GEMM. (unchanged: grid 512, K=128/block, 32-row
// chunks, double-buffered 66 KB LDS; DMA-bound at the W1 streaming floor.)
// ---------------------------------------------------------------------------
__global__
__attribute__((amdgpu_flat_work_group_size(256, 256)))
void fc1_mfma(const _Float16* __restrict__ h_t, const float* __restrict__ W1,
              _Float16* __restrict__ partials)
{
    __shared__ float w1s[2][32][258];          // 66048 B
    const int tid  = threadIdx.x;
    const int wave = tid >> 6;                 // 0..3
    const int lane = tid & 63;
    const int t16  = lane & 15;
    const int q    = lane >> 4;
    const int i0   = blockIdx.x * 128;

    f32x4 acc[4][4];
#pragma unroll
    for (int mt = 0; mt < 4; ++mt)
#pragma unroll
        for (int nt = 0; nt < 4; ++nt)
            acc[mt][nt] = (f32x4){0.f, 0.f, 0.f, 0.f};

    // prologue: DMA chunk 0 (each wave stages 8 rows of 1 KB)
#pragma unroll
    for (int r = 0; r < 8; ++r) {
        int row = wave * 8 + r;
        load_lds16(W1 + (size_t)(i0 + row) * 256 + lane * 4, &w1s[0][row][0]);
    }
    __syncthreads();                           // drains chunk-0 DMA

#pragma unroll 1
    for (int c = 0; c < 4; ++c) {
        const int buf = c & 1;
        const int cb  = i0 + c * 32;

        // A-frags issued first so their latency overlaps the DMA
        half8_t A[4];
#pragma unroll
        for (int mt = 0; mt < 4; ++mt)
            A[mt] = *(const half8_t*)(h_t
                + (size_t)(mt * 16 + t16) * 65536 + cb + q * 8);

        if (c < 3) {
#pragma unroll
            for (int r = 0; r < 8; ++r) {
                int row = wave * 8 + r;
                load_lds16(W1 + (size_t)(cb + 32 + row) * 256 + lane * 4,
                           &w1s[buf ^ 1][row][0]);
            }
        }

#pragma unroll
        for (int nt = 0; nt < 4; ++nt) {
            int j = (wave * 4 + nt) * 16 + t16;
            half8_t Bf;
#pragma unroll
            for (int i = 0; i < 8; ++i)
                Bf[i] = (_Float16)w1s[buf][q * 8 + i][j];
#pragma unroll
            for (int mt = 0; mt < 4; ++mt)
                acc[mt][nt] = MFMA32(A[mt], Bf, acc[mt][nt]);
        }
        __syncthreads();                       // sync + drain next-chunk DMA
    }

    _Float16* pb = partials + (size_t)blockIdx.x * 16384;
#pragma unroll
    for (int mt = 0; mt < 4; ++mt)
#pragma unroll
        for (int nt = 0; nt < 4; ++nt)
#pragma unroll
            for (int r = 0; r < 4; ++r)
                pb[(mt * 16 + 4 * q + r) * 256 + (wave * 4 + nt) * 16 + t16] =
                    (_Float16)acc[mt][nt][r];
}

// ---------------------------------------------------------------------------
// Kernel 3: fused partial-reduce + bias + tail MLP + softmax. (unchanged)
// ---------------------------------------------------------------------------
__global__ __launch_bounds__(1024) void mlp_tail(
    const _Float16* __restrict__ partials, const float* __restrict__ b1,
    const float* __restrict__ W2, const float* __restrict__ b2,
    const float* __restrict__ W3, const float* __restrict__ b3,
    float* __restrict__ out)
{
    __shared__ float x1p[16][256];
    __shared__ float x1s[256];
    __shared__ float x2q[32][33];
    __shared__ float x2s[32];
    __shared__ float lg[2];
    const int b = blockIdx.x, tid = threadIdx.x;
    const int kg = tid >> 6, l64 = tid & 63;
    const int j0 = l64 * 4;

    const _Float16* p = partials + (size_t)(kg * 32) * 16384 + (size_t)b * 256 + j0;
    float s0 = 0.f, s1 = 0.f, s2 = 0.f, s3 = 0.f;
#pragma unroll
    for (int k = 0; k < 32; ++k) {
        half4_t v = *(const half4_t*)(p + (size_t)k * 16384);
        s0 += (float)v[0]; s1 += (float)v[1]; s2 += (float)v[2]; s3 += (float)v[3];
    }
    x1p[kg][j0 + 0] = s0;
    x1p[kg][j0 + 1] = s1;
    x1p[kg][j0 + 2] = s2;
    x1p[kg][j0 + 3] = s3;
    __syncthreads();

    if (tid < 256) {
        float t = b1[tid];
#pragma unroll
        for (int g = 0; g < 16; ++g) t += x1p[g][tid];
        x1s[tid] = fmaxf(t, 0.f);
    }
    __syncthreads();

    const int j2 = tid & 31, g2 = tid >> 5;
    float s = 0.f;
#pragma unroll
    for (int k = g2 * 8; k < g2 * 8 + 8; ++k) s += x1s[k] * W2[k * 32 + j2];
    x2q[g2][j2] = s;
    __syncthreads();
    if (tid < 32) {
        float t = b2[tid];
#pragma unroll
        for (int g = 0; g < 32; ++g) t += x2q[g][tid];
        x2s[tid] = fmaxf(t, 0.f);
    }
    __syncthreads();
    if (tid < 2) {
        float t = b3[tid];
#pragma unroll
        for (int k = 0; k < 32; ++k) t += x2s[k] * W3[k * 2 + tid];
        lg[tid] = t;
    }
    __syncthreads();
    if (tid == 0) {
        float mx = fmaxf(lg[0], lg[1]);
        float e0 = __expf(lg[0] - mx), e1 = __expf(lg[1] - mx);
        float inv = 1.0f / (e0 + e1);
        out[b * 2 + 0] = e0 * inv;
        out[b * 2 + 1] = e1 * inv;
    }
}

// ---------------------------------------------------------------------------
extern "C" void kernel_launch(void* const* d_in, const int* in_sizes, int n_in,
                              void* d_out, int out_size, void* d_ws, size_t ws_size,
                              hipStream_t stream) {
    const float* inputs = (const float*)d_in[0];
    const float* Wn = (const float*)d_in[1];
    const float* Wg = (const float*)d_in[2];
    const float* Ug = (const float*)d_in[3];
    const float* bg = (const float*)d_in[4];
    const float* Wc = (const float*)d_in[5];
    const float* Uc = (const float*)d_in[6];
    const float* bc = (const float*)d_in[7];
    const float* We = (const float*)d_in[8];
    const float* be = (const float*)d_in[9];
    const float* W1 = (const float*)d_in[10];
    const float* b1 = (const float*)d_in[11];
    const float* W2 = (const float*)d_in[12];
    const float* b2 = (const float*)d_in[13];
    const float* W3 = (const float*)d_in[14];
    const float* b3 = (const float*)d_in[15];
    float* out = (float*)d_out;

    // ws: h_t f16 [64][65536] = 8 MB; partials f16 [512][64][256] = 16 MB
    _Float16* h_t      = (_Float16*)d_ws;
    _Float16* partials = (_Float16*)((char*)d_ws + (size_t)64 * 65536 * 2);

    ugrnn_mfma<<<2048, 256, 0, stream>>>(inputs, Wn, Wg, Ug, bg, Wc, Uc, bc,
                                         We, be, h_t);
    fc1_mfma<<<512, 256, 0, stream>>>(h_t, W1, partials);
    mlp_tail<<<64, 1024, 0, stream>>>(partials, b1, W2, b2, W3, b3, out);
}

// Round 10
// 178.366 us; speedup vs baseline: 1.3844x; 1.0008x over previous
//
#include <hip/hip_runtime.h>

typedef _Float16 half8_t __attribute__((ext_vector_type(8)));
typedef _Float16 half4_t __attribute__((ext_vector_type(4)));
typedef __fp16   fp16x2  __attribute__((ext_vector_type(2)));
typedef float    f32x4  __attribute__((ext_vector_type(4)));
typedef float    f32x4u __attribute__((ext_vector_type(4), aligned(4)));

#define MFMA32(a, b, c) __builtin_amdgcn_mfma_f32_16x16x32_f16((a), (b), (c), 0, 0, 0)
#define MFMA16(a, b, c) __builtin_amdgcn_mfma_f32_16x16x16f16((a), (b), (c), 0, 0, 0)

// async global->LDS DMA: LDS dst = wave-uniform base + lane*width (HW rule);
// global src carries the per-lane offset explicitly.
__device__ __forceinline__ void load_lds16(const void* g, void* l) {
    __builtin_amdgcn_global_load_lds(
        (const __attribute__((address_space(1))) unsigned int*)g,
        (__attribute__((address_space(3))) unsigned int*)l, 16, 0, 0);
}

// 4x f32 -> half4: two v_cvt_pkrtz into an adjacent VGPR pair (union pun)
__device__ __forceinline__ half4_t pk4(f32x4 v) {
    union { fp16x2 h2[2]; half4_t h4; } u;
    u.h2[0] = __builtin_amdgcn_cvt_pkrtz(v[0], v[1]);
    u.h2[1] = __builtin_amdgcn_cvt_pkrtz(v[2], v[3]);
    return u.h4;
}
__device__ __forceinline__ f32x4 exp2v(f32x4 v) {
    f32x4 r;
    r[0] = __builtin_amdgcn_exp2f(v[0]);
    r[1] = __builtin_amdgcn_exp2f(v[1]);
    r[2] = __builtin_amdgcn_exp2f(v[2]);
    r[3] = __builtin_amdgcn_exp2f(v[3]);
    return r;
}
__device__ __forceinline__ f32x4 rcpv(f32x4 v) {
    f32x4 r;
    r[0] = __builtin_amdgcn_rcpf(v[0]);
    r[1] = __builtin_amdgcn_rcpf(v[1]);
    r[2] = __builtin_amdgcn_rcpf(v[2]);
    r[3] = __builtin_amdgcn_rcpf(v[3]);
    return r;
}

// ---------------------------------------------------------------------------
// Kernel 1: UGRNN recurrence, operand-swapped MFMA (D^T = W^T X^T).
// R10: ONE 16-token tile per wave (was 2), grid 4096. R9's live-state count
// (frags 26 + state 24 + step temporaries ~30) lands ~90-110 VGPR -> over
// the 64-VGPR cliff -> 4 waves/SIMD resident. Halving per-wave state should
// fit <=64 VGPR -> 8 waves/SIMD; total chip-wide instruction count is
// unchanged, so this isolates occupancy x latency from issue-demand.
// Math identical to R9: chained gate MFMAs, e-register eliminated
// (x_next = m1 - 2*rc, m1 = m+1 hoisted), log2e folded into weights,
// shared rcp per 3 sigmoids, pk4 union pun, zero LDS.
// Layouts (verified R1): MFMA16 B frag [k=4q+i][n=t16] == C/D [4q+r][t16];
// MFMA32 A [m=t16][k=8q+i], B [k=8q+i][n=t16], D [m=4q+r][n=t16].
// ---------------------------------------------------------------------------
__global__
__attribute__((amdgpu_flat_work_group_size(256, 256)))
void ugrnn_mfma(
    const float* __restrict__ inputs,
    const float* __restrict__ Wn, const float* __restrict__ Wg,
    const float* __restrict__ Ug, const float* __restrict__ bg,
    const float* __restrict__ Wc, const float* __restrict__ Uc,
    const float* __restrict__ bc, const float* __restrict__ We,
    const float* __restrict__ be, _Float16* __restrict__ h_t)
{
    const int wave = threadIdx.x >> 6;
    const int lane = threadIdx.x & 63;
    const int t16  = lane & 15;
    const int q    = lane >> 4;

    const int tile = blockIdx.x * 4 + wave;    // [0, 16384)
    const int b    = tile >> 8;                // 256 tiles per batch
    const int n0   = (tile & 255) << 4;

    const float NL2E = -1.44269504f;   // -log2(e)   : sigmoid arg scale
    const float TL2E =  2.88539008f;   // 2*log2(e)  : tanh arg scale

    const float* gsrc = inputs + (size_t)tile * 544;
    const f32x4 zc  = {0.f, 0.f, 0.f, 0.f};
    const f32x4 one = {1.f, 1.f, 1.f, 1.f};

    // weight A-fragments (A[m=t16][k] = W[k][t16]); fly with the input loads
    half8_t An;
#pragma unroll
    for (int i = 0; i < 8; ++i)
        An[i] = (_Float16)Wn[(q * 8 + i) * 16 + t16];

    half4_t Awg, Aug, Awc, Auc, Awe;
#pragma unroll
    for (int i = 0; i < 4; ++i) {
        const int k = 4 * q + i;
        Awg[i] = (_Float16)(Wg[k * 16 + t16] * NL2E);
        Aug[i] = (_Float16)(Ug[k * 16 + t16] * NL2E);
        Awc[i] = (_Float16)(Wc[k * 16 + t16] * TL2E);
        Auc[i] = (_Float16)(Uc[k * 16 + t16] * TL2E);
        Awe[i] = (_Float16)(We[k * 16 + t16] * TL2E);
    }
    f32x4 bgC, bcC, beC;
#pragma unroll
    for (int r = 0; r < 4; ++r) {
        bgC[r] = bg[4 * q + r] * NL2E;
        bcC[r] = bc[4 * q + r] * TL2E;
        beC[r] = be[4 * q + r] * TL2E;
    }

    // ---- direct-from-global fragment/state loads (once) ----
    f32x4 m1, h, x;
    {
        const float* rp = gsrc + t16 * 34;
        f32x4 x0 = *(const f32x4u*)(rp + 1 + q * 8);
        f32x4 x1 = *(const f32x4u*)(rp + 5 + q * 8);
        union { half4_t h4[2]; half8_t h8; } bx;
        bx.h4[0] = pk4(x0);
        bx.h4[1] = pk4(x1);
        f32x4 m = MFMA32(An, bx.h8, zc);     // B[k=8q+i][n=t16]
        const float hv = rp[0];
        const float ev = rp[33];
        h  = (f32x4){hv, hv, hv, hv};
        m1 = m + one;                         // hoisted: x_next = m1 - 2*rc
        x  = m + (f32x4){ev, ev, ev, ev};     // initial x = m + e0
    }

#pragma unroll 1
    for (int step = 0; step < 8; ++step) {
        half4_t xB = pk4(x);
        half4_t hB = pk4(h);
        // chained via C operand: latency is hidden by co-resident waves
        f32x4 gp = MFMA16(Aug, hB, MFMA16(Awg, xB, bgC));
        f32x4 cp = MFMA16(Auc, hB, MFMA16(Awc, xB, bcC));
        const f32x4 Ae = one + exp2v(gp);
        const f32x4 Be = one + exp2v(cp);
        if (step < 7) {
            f32x4 ep = MFMA16(Awe, xB, beC);
            const f32x4 Ce = one + exp2v(ep);
            const f32x4 BC = Be * Ce;
            const f32x4 rr = rcpv(Ae * BC);
            const f32x4 gv = rr * BC;                  // sigma(gate)
            const f32x4 cv = one - 2.0f * (rr * (Ae * Ce)); // tanh(c)
            h = cv + gv * (h - cv);
            x = m1 - 2.0f * (rr * (Ae * Be));          // m + tanh(e-pre)
        } else {
            const f32x4 rr = rcpv(Ae * Be);
            const f32x4 gv = rr * Be;
            const f32x4 cv = one - 2.0f * (rr * Ae);
            h = cv + gv * (h - cv);
        }
    }

    // coalesced store: 64 lanes tile 512 B contiguously
    *(half4_t*)(h_t + (size_t)b * 65536 + (size_t)(n0 + t16) * 16 + 4 * q) =
        pk4(h);
}

// ---------------------------------------------------------------------------
// Kernel 2: FC1 partial GEMM. (unchanged: grid 512, K=128/block, 32-row
// chunks, double-buffered 66 KB LDS; at its ~14 us traffic floor.)
// ---------------------------------------------------------------------------
__global__
__attribute__((amdgpu_flat_work_group_size(256, 256)))
void fc1_mfma(const _Float16* __restrict__ h_t, const float* __restrict__ W1,
              _Float16* __restrict__ partials)
{
    __shared__ float w1s[2][32][258];          // 66048 B
    const int tid  = threadIdx.x;
    const int wave = tid >> 6;                 // 0..3
    const int lane = tid & 63;
    const int t16  = lane & 15;
    const int q    = lane >> 4;
    const int i0   = blockIdx.x * 128;

    f32x4 acc[4][4];
#pragma unroll
    for (int mt = 0; mt < 4; ++mt)
#pragma unroll
        for (int nt = 0; nt < 4; ++nt)
            acc[mt][nt] = (f32x4){0.f, 0.f, 0.f, 0.f};

    // prologue: DMA chunk 0 (each wave stages 8 rows of 1 KB)
#pragma unroll
    for (int r = 0; r < 8; ++r) {
        int row = wave * 8 + r;
        load_lds16(W1 + (size_t)(i0 + row) * 256 + lane * 4, &w1s[0][row][0]);
    }
    __syncthreads();                           // drains chunk-0 DMA

#pragma unroll 1
    for (int c = 0; c < 4; ++c) {
        const int buf = c & 1;
        const int cb  = i0 + c * 32;

        // A-frags issued first so their latency overlaps the DMA
        half8_t A[4];
#pragma unroll
        for (int mt = 0; mt < 4; ++mt)
            A[mt] = *(const half8_t*)(h_t
                + (size_t)(mt * 16 + t16) * 65536 + cb + q * 8);

        if (c < 3) {
#pragma unroll
            for (int r = 0; r < 8; ++r) {
                int row = wave * 8 + r;
                load_lds16(W1 + (size_t)(cb + 32 + row) * 256 + lane * 4,
                           &w1s[buf ^ 1][row][0]);
            }
        }

#pragma unroll
        for (int nt = 0; nt < 4; ++nt) {
            int j = (wave * 4 + nt) * 16 + t16;
            half8_t Bf;
#pragma unroll
            for (int i = 0; i < 8; ++i)
                Bf[i] = (_Float16)w1s[buf][q * 8 + i][j];
#pragma unroll
            for (int mt = 0; mt < 4; ++mt)
                acc[mt][nt] = MFMA32(A[mt], Bf, acc[mt][nt]);
        }
        __syncthreads();                       // sync + drain next-chunk DMA
    }

    _Float16* pb = partials + (size_t)blockIdx.x * 16384;
#pragma unroll
    for (int mt = 0; mt < 4; ++mt)
#pragma unroll
        for (int nt = 0; nt < 4; ++nt)
#pragma unroll
            for (int r = 0; r < 4; ++r)
                pb[(mt * 16 + 4 * q + r) * 256 + (wave * 4 + nt) * 16 + t16] =
                    (_Float16)acc[mt][nt][r];
}

// ---------------------------------------------------------------------------
// Kernel 3: fused partial-reduce + bias + tail MLP + softmax. (unchanged)
// ---------------------------------------------------------------------------
__global__ __launch_bounds__(1024) void mlp_tail(
    const _Float16* __restrict__ partials, const float* __restrict__ b1,
    const float* __restrict__ W2, const float* __restrict__ b2,
    const float* __restrict__ W3, const float* __restrict__ b3,
    float* __restrict__ out)
{
    __shared__ float x1p[16][256];
    __shared__ float x1s[256];
    __shared__ float x2q[32][33];
    __shared__ float x2s[32];
    __shared__ float lg[2];
    const int b = blockIdx.x, tid = threadIdx.x;
    const int kg = tid >> 6, l64 = tid & 63;
    const int j0 = l64 * 4;

    const _Float16* p = partials + (size_t)(kg * 32) * 16384 + (size_t)b * 256 + j0;
    float s0 = 0.f, s1 = 0.f, s2 = 0.f, s3 = 0.f;
#pragma unroll
    for (int k = 0; k < 32; ++k) {
        half4_t v = *(const half4_t*)(p + (size_t)k * 16384);
        s0 += (float)v[0]; s1 += (float)v[1]; s2 += (float)v[2]; s3 += (float)v[3];
    }
    x1p[kg][j0 + 0] = s0;
    x1p[kg][j0 + 1] = s1;
    x1p[kg][j0 + 2] = s2;
    x1p[kg][j0 + 3] = s3;
    __syncthreads();

    if (tid < 256) {
        float t = b1[tid];
#pragma unroll
        for (int g = 0; g < 16; ++g) t += x1p[g][tid];
        x1s[tid] = fmaxf(t, 0.f);
    }
    __syncthreads();

    const int j2 = tid & 31, g2 = tid >> 5;
    float s = 0.f;
#pragma unroll
    for (int k = g2 * 8; k < g2 * 8 + 8; ++k) s += x1s[k] * W2[k * 32 + j2];
    x2q[g2][j2] = s;
    __syncthreads();
    if (tid < 32) {
        float t = b2[tid];
#pragma unroll
        for (int g = 0; g < 32; ++g) t += x2q[g][tid];
        x2s[tid] = fmaxf(t, 0.f);
    }
    __syncthreads();
    if (tid < 2) {
        float t = b3[tid];
#pragma unroll
        for (int k = 0; k < 32; ++k) t += x2s[k] * W3[k * 2 + tid];
        lg[tid] = t;
    }
    __syncthreads();
    if (tid == 0) {
        float mx = fmaxf(lg[0], lg[1]);
        float e0 = __expf(lg[0] - mx), e1 = __expf(lg[1] - mx);
        float inv = 1.0f / (e0 + e1);
        out[b * 2 + 0] = e0 * inv;
        out[b * 2 + 1] = e1 * inv;
    }
}

// ---------------------------------------------------------------------------
extern "C" void kernel_launch(void* const* d_in, const int* in_sizes, int n_in,
                              void* d_out, int out_size, void* d_ws, size_t ws_size,
                              hipStream_t stream) {
    const float* inputs = (const float*)d_in[0];
    const float* Wn = (const float*)d_in[1];
    const float* Wg = (const float*)d_in[2];
    const float* Ug = (const float*)d_in[3];
    const float* bg = (const float*)d_in[4];
    const float* Wc = (const float*)d_in[5];
    const float* Uc = (const float*)d_in[6];
    const float* bc = (const float*)d_in[7];
    const float* We = (const float*)d_in[8];
    const float* be = (const float*)d_in[9];
    const float* W1 = (const float*)d_in[10];
    const float* b1 = (const float*)d_in[11];
    const float* W2 = (const float*)d_in[12];
    const float* b2 = (const float*)d_in[13];
    const float* W3 = (const float*)d_in[14];
    const float* b3 = (const float*)d_in[15];
    float* out = (float*)d_out;

    // ws: h_t f16 [64][65536] = 8 MB; partials f16 [512][64][256] = 16 MB
    _Float16* h_t      = (_Float16*)d_ws;
    _Float16* partials = (_Float16*)((char*)d_ws + (size_t)64 * 65536 * 2);

    ugrnn_mfma<<<4096, 256, 0, stream>>>(inputs, Wn, Wg, Ug, bg, Wc, Uc, bc,
                                         We, be, h_t);
    fc1_mfma<<<512, 256, 0, stream>>>(h_t, W1, partials);
    mlp_tail<<<64, 1024, 0, stream>>>(partials, b1, W2, b2, W3, b3, out);
}